// Round 6
// baseline (134.438 us; speedup 1.0000x reference)
//
#include <hip/hip_runtime.h>
#include <math.h>

#define B_ROWS 8192
#define NU 512
#define FEATS 64
#define RPB 8      // rows per block (= waves per block)
#define TOPK_K 8

typedef unsigned long long ull;

__device__ __forceinline__ ull shfl_xor_u64(ull x, int m) {
  int lo = (int)(unsigned)(x & 0xffffffffULL);
  int hi = (int)(unsigned)(x >> 32);
  lo = __shfl_xor(lo, m, 64);
  hi = __shfl_xor(hi, m, 64);
  return ((ull)(unsigned)hi << 32) | (ull)(unsigned)lo;
}

template <int S>
__device__ __forceinline__ void inreg_pass(ull v[8], unsigned lane, unsigned k) {
#pragma unroll
  for (int i = 0; i < 8; ++i) {
    if ((i & S) == 0) {
      const int ip = i | S;
      const unsigned e = (lane << 3) | (unsigned)i;
      const bool asc = ((e & k) == 0);
      const ull a = v[i], b = v[ip];
      const bool lt = a < b;
      const ull lo2 = lt ? a : b;
      const ull hi2 = lt ? b : a;
      v[i]  = asc ? lo2 : hi2;
      v[ip] = asc ? hi2 : lo2;
    }
  }
}

__device__ __forceinline__ void cross_pass(ull v[8], unsigned lane, unsigned m, unsigned k) {
#pragma unroll
  for (int i = 0; i < 8; ++i) {
    const ull o = shfl_xor_u64(v[i], (int)m);
    const unsigned e = (lane << 3) | (unsigned)i;
    const bool takeMin = (((lane & m) == 0) == ((e & k) == 0));
    const bool keep = ((v[i] < o) == takeMin);
    v[i] = keep ? v[i] : o;
  }
}

__global__ __launch_bounds__(512)
void lcm_kernel(const float* __restrict__ x, const float* __restrict__ c,
                float* __restrict__ out) {
#pragma clang fp contract(off)
  __shared__ float xs[RPB * FEATS];
  __shared__ ull keys[RPB * NU];

  const int t = threadIdx.x;
  const int r0 = blockIdx.x * RPB;

  xs[t] = x[r0 * FEATS + t];
  __syncthreads();

  // ---- distances: XLA-CPU-style AVX-512 vectorized reduce, replicated bitwise ----
  // t_f = x_f - c_f (f32); 16 lane-accumulators over 4 sequential chunks (NO fma):
  //   r[j] = t[j]^2; r[j] += t[16k+j]^2 for k=1..3
  // horizontal shuffle-halving tree:
  //   s8[j]=r[j]+r[j+8]; s4[j]=s8[j]+s8[j+4]; s2[j]=s4[j]+s4[j+2]; tot=s2[0]+s2[1]
  // d = sqrtf(tot), correctly rounded.
  {
    const int n = t;
    float cs[FEATS];
    const float4* c4 = (const float4*)c + (size_t)n * 16;
#pragma unroll
    for (int q = 0; q < 16; ++q) {
      const float4 v = c4[q];
      cs[q * 4 + 0] = v.x; cs[q * 4 + 1] = v.y;
      cs[q * 4 + 2] = v.z; cs[q * 4 + 3] = v.w;
    }
    float* o_d = out;
#pragma unroll
    for (int r = 0; r < RPB; ++r) {
      const float* xr = xs + r * FEATS;
      float rr[16];
#pragma unroll
      for (int j = 0; j < 16; ++j) {
        const float tt = xr[j] - cs[j];
        rr[j] = tt * tt;
      }
#pragma unroll
      for (int k = 1; k < 4; ++k) {
#pragma unroll
        for (int j = 0; j < 16; ++j) {
          const float tt = xr[16 * k + j] - cs[16 * k + j];
          rr[j] = rr[j] + tt * tt;
        }
      }
      float s8[8], s4[4], s2[2];
#pragma unroll
      for (int j = 0; j < 8; ++j) s8[j] = rr[j] + rr[j + 8];
#pragma unroll
      for (int j = 0; j < 4; ++j) s4[j] = s8[j] + s8[j + 4];
#pragma unroll
      for (int j = 0; j < 2; ++j) s2[j] = s4[j] + s4[j + 2];
      const float tot = s2[0] + s2[1];
      const float dv = (float)__builtin_sqrt((double)tot);
      o_d[(size_t)(r0 + r) * NU + n] = dv;
      // key: f32 bits (positive -> value-ordered) high 32, idx low -> stable tiebreak
      keys[r * NU + n] = ((ull)__float_as_uint(dv) << 32) | (ull)n;
    }
  }
  __syncthreads();

  // ---- per-wave stable bitonic sort of 512 keys (wave w = row w) ----
  {
    const unsigned lane = (unsigned)(t & 63);
    const int w = t >> 6;

    ull v[8];
#pragma unroll
    for (int i = 0; i < 8; ++i) v[i] = keys[w * NU + i * 64 + (int)lane];

    inreg_pass<1>(v, lane, 2u);
    inreg_pass<2>(v, lane, 4u);
    inreg_pass<1>(v, lane, 4u);
    inreg_pass<4>(v, lane, 8u);
    inreg_pass<2>(v, lane, 8u);
    inreg_pass<1>(v, lane, 8u);
    for (unsigned k = 16; k <= 512; k <<= 1) {
      for (unsigned j = k >> 1; j >= 8; j >>= 1) cross_pass(v, lane, j >> 3, k);
      inreg_pass<4>(v, lane, k);
      inreg_pass<2>(v, lane, k);
      inreg_pass<1>(v, lane, k);
    }

    const int row = r0 + w;
    float* o_is = out + (size_t)B_ROWS * NU;
    float* o_k  = o_is + (size_t)B_ROWS * NU;
    float* o_z  = o_k + (size_t)B_ROWS * NU;
    float* o_xc = o_z + (size_t)B_ROWS * NU;

    int idxv[8];
#pragma unroll
    for (int i = 0; i < 8; ++i) idxv[i] = (int)(v[i] & 0x1ffULL);

    float4 fa, fb;
    fa.x = (float)idxv[0]; fa.y = (float)idxv[1];
    fa.z = (float)idxv[2]; fa.w = (float)idxv[3];
    fb.x = (float)idxv[4]; fb.y = (float)idxv[5];
    fb.z = (float)idxv[6]; fb.w = (float)idxv[7];
    float4* isrow = (float4*)(o_is + (size_t)row * NU);
    isrow[lane * 2 + 0] = fa;
    isrow[lane * 2 + 1] = fb;

#pragma unroll
    for (int i = 0; i < 8; ++i) {
      const int e = (int)lane * 8 + i;
      o_k[(size_t)row * NU + idxv[i]] = (float)e;
      o_z[(size_t)row * NU + idxv[i]] = (e < TOPK_K) ? (1.0f / (float)(i + 1)) : 0.0f;
    }

    int top = idxv[0];
    top = __shfl(top, 0, 64);
    o_xc[(size_t)row * FEATS + (int)lane] = c[top * FEATS + (int)lane];
  }
}

extern "C" void kernel_launch(void* const* d_in, const int* in_sizes, int n_in,
                              void* d_out, int out_size, void* d_ws, size_t ws_size,
                              hipStream_t stream) {
  const float* x = (const float*)d_in[0];
  const float* c = (const float*)d_in[1];
  float* out = (float*)d_out;
  lcm_kernel<<<dim3(B_ROWS / RPB), dim3(512), 0, stream>>>(x, c, out);
}